// Round 9
// baseline (108.015 us; speedup 1.0000x reference)
//
#include <hip/hip_runtime.h>
#include <hip/hip_bf16.h>

// AlgebraicLinear: out[m, o] = sum_i x[m, i] * w[o, i] + bias[o]
// M = 32768, K = 256, N = 256, fp32 in/out, bf16 MFMA inside.
// ROUND 9 PROBE: round-5 kernel, launched TWICE (idempotent) to measure
// true kernel time through the top-5 blind spot: k = dur_us - 91.3.

typedef __attribute__((ext_vector_type(8))) short short8;   // 8 bf16 (4 VGPRs)
typedef __attribute__((ext_vector_type(4))) short short4v;  // 4 bf16 (2 VGPRs)
typedef __attribute__((ext_vector_type(4))) float f32x4;

#define K_DIM 256
#define N_DIM 256
#define BM 128
#define THREADS 512   // 8 waves

__device__ __forceinline__ short bf16bits(float f) {
  __bf16 h = (__bf16)f;
  return __builtin_bit_cast(short, h);
}

__global__ __launch_bounds__(THREADS, 2)
void AlgebraicLinear_kernel(const float* __restrict__ x,
                            const float* __restrict__ w,
                            const float* __restrict__ bias,
                            float* __restrict__ out) {
  // bf16 x-tile, XOR-swizzled: (row*512 + kbyte) ^ ((row&7)<<4). 64 KiB.
  __shared__ char lds[BM * K_DIM * 2];

  const int tid  = threadIdx.x;
  const int lane = tid & 63;
  const int wid  = tid >> 6;    // wave 0..7 -> owns n-cols [wid*32, wid*32+32)
  const int g    = lane >> 4;   // 0..3 (k-group)
  const int r    = lane & 15;

  const long mbase = (long)blockIdx.x * BM;

  // ---- W -> register B-fragments (2 n-tiles x 8 k-tiles), fp32->bf16 ----
  // B-frag lane layout: B[k = kt*32 + g*8 + i][col = nt*16 + r] = W[col][k]
  short8 bfrag[2][8];
  #pragma unroll
  for (int nt = 0; nt < 2; ++nt) {
    const float* wr = w + (size_t)(wid * 32 + nt * 16 + r) * K_DIM;
    #pragma unroll
    for (int kt = 0; kt < 8; ++kt) {
      const float4* p = reinterpret_cast<const float4*>(wr + kt * 32 + g * 8);
      float4 lo = p[0];
      float4 hi = p[1];
      short8 f;
      f[0] = bf16bits(lo.x); f[1] = bf16bits(lo.y);
      f[2] = bf16bits(lo.z); f[3] = bf16bits(lo.w);
      f[4] = bf16bits(hi.x); f[5] = bf16bits(hi.y);
      f[6] = bf16bits(hi.z); f[7] = bf16bits(hi.w);
      bfrag[nt][kt] = f;
    }
  }
  const float b0 = bias[wid * 32 + r];
  const float b1 = bias[wid * 32 + 16 + r];

  // ---- stage x tile: 128 rows x 256 fp32 -> bf16 LDS (swizzled) ----
  #pragma unroll
  for (int it = 0; it < (BM * K_DIM / 4) / THREADS; ++it) {  // 16 iters
    int c   = it * THREADS + tid;
    int row = c >> 6;
    int k4  = (c & 63) * 4;
    float4 v = *reinterpret_cast<const float4*>(x + (mbase + row) * K_DIM + k4);
    short4v s;
    s[0] = bf16bits(v.x); s[1] = bf16bits(v.y);
    s[2] = bf16bits(v.z); s[3] = bf16bits(v.w);
    int addr = (row * 512 + k4 * 2) ^ ((row & 7) << 4);
    *reinterpret_cast<short4v*>(lds + addr) = s;
  }
  __syncthreads();

  // ---- compute: 8 m-tiles of 16 rows each ----
  const int ncol = wid * 32 + r;
  #pragma unroll 1
  for (int mt = 0; mt < 8; ++mt) {
    short8 a[8];
    const int arow = mt * 16 + r;
    const int abase = arow * 512;
    const int aswz = (arow & 7) << 4;
    #pragma unroll
    for (int kt = 0; kt < 8; ++kt) {
      int addr = (abase + kt * 64 + g * 16) ^ aswz;
      a[kt] = *reinterpret_cast<const short8*>(lds + addr);
    }
    f32x4 acc0 = {0.f, 0.f, 0.f, 0.f};
    f32x4 acc1 = {0.f, 0.f, 0.f, 0.f};
    #pragma unroll
    for (int kt = 0; kt < 8; ++kt) {
      acc0 = __builtin_amdgcn_mfma_f32_16x16x32_bf16(a[kt], bfrag[0][kt], acc0, 0, 0, 0);
      acc1 = __builtin_amdgcn_mfma_f32_16x16x32_bf16(a[kt], bfrag[1][kt], acc1, 0, 0, 0);
    }
    // D layout: row = g*4 + rr, col = r (within tile)
    float* op = out + (mbase + mt * 16 + g * 4) * N_DIM + ncol;
    #pragma unroll
    for (int rr = 0; rr < 4; ++rr) {
      op[rr * N_DIM]      = acc0[rr] + b0;
      op[rr * N_DIM + 16] = acc1[rr] + b1;
    }
  }
}

extern "C" void kernel_launch(void* const* d_in, const int* in_sizes, int n_in,
                              void* d_out, int out_size, void* d_ws, size_t ws_size,
                              hipStream_t stream) {
  const float* x    = (const float*)d_in[0];  // (8, 4096, 256)
  const float* w    = (const float*)d_in[1];  // (256, 256)
  const float* bias = (const float*)d_in[2];  // (256,)
  float* out = (float*)d_out;                 // (8, 4096, 256)

  const int M = 8 * 4096;
  dim3 grid(M / BM);   // 256 blocks = 1 per CU
  dim3 block(THREADS); // 8 waves
  // PROBE: launch twice (idempotent). dur_us - 91.3 = single-kernel time.
  AlgebraicLinear_kernel<<<grid, block, 0, stream>>>(x, w, bias, out);
  AlgebraicLinear_kernel<<<grid, block, 0, stream>>>(x, w, bias, out);
}

// Round 16
// 98.312 us; speedup vs baseline: 1.0987x; 1.0987x over previous
//
#include <hip/hip_runtime.h>
#include <hip/hip_bf16.h>

// AlgebraicLinear: out[m, o] = sum_i x[m, i] * w[o, i] + bias[o]
// M = 32768, K = 256, N = 256, fp32 in/out, bf16 MFMA inside.
// Round-10: rolling 16-row pipeline. Per iter: prefetch tile mt+1 (global->regs),
// ds_read+MFMA+store tile mt, cvt+ds_write mt+1, one barrier. 2x8KB LDS dbuf.

typedef __attribute__((ext_vector_type(8))) short short8;   // 8 bf16
typedef __attribute__((ext_vector_type(4))) short short4v;  // 4 bf16
typedef __attribute__((ext_vector_type(4))) float f32x4;

#define K_DIM 256
#define N_DIM 256
#define BM 128
#define THREADS 512   // 8 waves

__device__ __forceinline__ short bf16bits(float f) {
  __bf16 h = (__bf16)f;
  return __builtin_bit_cast(short, h);
}

__global__ __launch_bounds__(THREADS, 2)
void AlgebraicLinear_kernel(const float* __restrict__ x,
                            const float* __restrict__ w,
                            const float* __restrict__ bias,
                            float* __restrict__ out) {
  // two 16-row bf16 buffers, XOR-swizzled rows of 512 B
  __shared__ char lds[2 * 16 * 512];

  const int tid  = threadIdx.x;
  const int lane = tid & 63;
  const int wid  = tid >> 6;    // wave 0..7 -> n-cols [wid*32, wid*32+32)
  const int g    = lane >> 4;   // 0..3
  const int r    = lane & 15;

  const long mbase = (long)blockIdx.x * BM;

  // stage addressing: thread covers chunks c0 = tid and c1 = tid + 512
  // (chunk = 4 floats; 64 chunks/row; 16 rows/tile)
  const int lr0 = tid >> 6;             // 0..7
  const int lr1 = (tid + 512) >> 6;     // 8..15
  const int cc  = (tid & 63) * 4;       // float index within row
  const int w0  = ((lr0 * 512 + cc * 2) ^ ((lr0 & 7) << 4));
  const int w1  = ((lr1 * 512 + cc * 2) ^ ((lr1 & 7) << 4));

  // ---- W -> register B-fragments (once per block) ----
  // B[k = kt*32 + g*8 + i][col = nt*16 + r] = W[col][k]
  short8 bfrag[2][8];
  #pragma unroll
  for (int nt = 0; nt < 2; ++nt) {
    const float* wr = w + (size_t)(wid * 32 + nt * 16 + r) * K_DIM;
    #pragma unroll
    for (int kt = 0; kt < 8; ++kt) {
      const float4* p = reinterpret_cast<const float4*>(wr + kt * 32 + g * 8);
      float4 lo = p[0];
      float4 hi = p[1];
      short8 f;
      f[0] = bf16bits(lo.x); f[1] = bf16bits(lo.y);
      f[2] = bf16bits(lo.z); f[3] = bf16bits(lo.w);
      f[4] = bf16bits(hi.x); f[5] = bf16bits(hi.y);
      f[6] = bf16bits(hi.z); f[7] = bf16bits(hi.w);
      bfrag[nt][kt] = f;
    }
  }
  const float b0 = bias[wid * 32 + r];
  const float b1 = bias[wid * 32 + 16 + r];
  const int ncol = wid * 32 + r;

  // ---- stage tile 0 into buf0 ----
  {
    float4 v0 = *reinterpret_cast<const float4*>(x + (mbase + lr0) * K_DIM + cc);
    float4 v1 = *reinterpret_cast<const float4*>(x + (mbase + lr1) * K_DIM + cc);
    short4v s0, s1;
    s0[0] = bf16bits(v0.x); s0[1] = bf16bits(v0.y);
    s0[2] = bf16bits(v0.z); s0[3] = bf16bits(v0.w);
    s1[0] = bf16bits(v1.x); s1[1] = bf16bits(v1.y);
    s1[2] = bf16bits(v1.z); s1[3] = bf16bits(v1.w);
    *reinterpret_cast<short4v*>(lds + w0) = s0;
    *reinterpret_cast<short4v*>(lds + w1) = s1;
  }
  __syncthreads();

  // ---- rolling pipeline over 8 m-tiles ----
  #pragma unroll
  for (int mt = 0; mt < 8; ++mt) {
    const int cur = (mt & 1) * 8192;
    const int nxt = ((mt + 1) & 1) * 8192;

    // 1) prefetch tile mt+1 (issue early; latency hides under MFMA+stores)
    float4 p0, p1;
    if (mt < 7) {
      const long rb = mbase + (mt + 1) * 16;
      p0 = *reinterpret_cast<const float4*>(x + (rb + lr0) * K_DIM + cc);
      p1 = *reinterpret_cast<const float4*>(x + (rb + lr1) * K_DIM + cc);
    }

    // 2) compute tile mt from buf[cur]
    short8 a[8];
    const int abase = r * 512;
    const int aswz  = (r & 7) << 4;
    #pragma unroll
    for (int kt = 0; kt < 8; ++kt)
      a[kt] = *reinterpret_cast<const short8*>(lds + cur + ((abase + kt * 64 + g * 16) ^ aswz));
    f32x4 c0 = {0.f, 0.f, 0.f, 0.f};
    f32x4 c1 = {0.f, 0.f, 0.f, 0.f};
    #pragma unroll
    for (int kt = 0; kt < 8; ++kt) {
      c0 = __builtin_amdgcn_mfma_f32_16x16x32_bf16(a[kt], bfrag[0][kt], c0, 0, 0, 0);
      c1 = __builtin_amdgcn_mfma_f32_16x16x32_bf16(a[kt], bfrag[1][kt], c1, 0, 0, 0);
    }

    // 3) store tile mt (fire-and-forget; overlaps prefetch completion)
    float* op = out + (mbase + mt * 16 + g * 4) * N_DIM + ncol;
    #pragma unroll
    for (int rr = 0; rr < 4; ++rr) {
      op[rr * N_DIM]      = c0[rr] + b0;
      op[rr * N_DIM + 16] = c1[rr] + b1;
    }

    // 4) cvt + ds_write tile mt+1 into buf[nxt]
    if (mt < 7) {
      short4v s0, s1;
      s0[0] = bf16bits(p0.x); s0[1] = bf16bits(p0.y);
      s0[2] = bf16bits(p0.z); s0[3] = bf16bits(p0.w);
      s1[0] = bf16bits(p1.x); s1[1] = bf16bits(p1.y);
      s1[2] = bf16bits(p1.z); s1[3] = bf16bits(p1.w);
      *reinterpret_cast<short4v*>(lds + nxt + w0) = s0;
      *reinterpret_cast<short4v*>(lds + nxt + w1) = s1;
      __syncthreads();
    }
  }
}

extern "C" void kernel_launch(void* const* d_in, const int* in_sizes, int n_in,
                              void* d_out, int out_size, void* d_ws, size_t ws_size,
                              hipStream_t stream) {
  const float* x    = (const float*)d_in[0];  // (8, 4096, 256)
  const float* w    = (const float*)d_in[1];  // (256, 256)
  const float* bias = (const float*)d_in[2];  // (256,)
  float* out = (float*)d_out;                 // (8, 4096, 256)

  const int M = 8 * 4096;
  dim3 grid(M / BM);   // 256 blocks = 1 per CU
  dim3 block(THREADS); // 8 waves
  AlgebraicLinear_kernel<<<grid, block, 0, stream>>>(x, w, bias, out);
}